// Round 12
// baseline (203.802 us; speedup 1.0000x reference)
//
#include <hip/hip_runtime.h>

// Problem constants: B=4, C_IN=C=64, H=W=128, K=3, SCALE=0.125, EPS=1e-5
#define NB 4
#define HWSZ 16384   // 128*128

// 16B vector with only 4B alignment guarantee (gfx9+ supports unaligned dwordx4)
typedef float f4u __attribute__((ext_vector_type(4), aligned(4)));
// fp16 vectors for the interleaved cols tensor (stored fp16, computed fp32)
typedef _Float16 h8 __attribute__((ext_vector_type(8)));

// icols layout (r9-verified): flat cols g = m*2^20 + n; plane m stride 2^21
// halfs; group (n>>2) holds 16B = F0..F3|B0..B3.
#define PLANE_H ((size_t)1 << 21)
#define HALO 168
#define CHUNK 2048
#define SPAN 2392   // staged elements per array: [h0-168, h0+2048+176)

// ---------------------------------------------------------------------------
// pw body: 1x1 conv (64 -> 64) + bias. 1024 blocks per op.
// ---------------------------------------------------------------------------
__device__ __forceinline__ void pw_body(int bid, int tid,
                                        const float* __restrict__ in,
                                        const float* __restrict__ w,
                                        const float* __restrict__ bias,
                                        float* __restrict__ out,
                                        float* wls) {
  int b = bid >> 8;
  int r = bid & 255;
  int oc = r >> 6;
  int pc = r & 63;
  int px4 = tid & 63;
  int og = tid >> 6;
  int px = (pc << 8) + (px4 << 2);
#pragma unroll
  for (int it = 0; it < 4; ++it)
    wls[(it << 8) + tid] = w[(oc << 10) + (it << 8) + tid];
  __syncthreads();
  int ob = (oc << 4) + (og << 2);
  float4 acc[4];
#pragma unroll
  for (int j = 0; j < 4; ++j) {
    float bv = bias[ob + j];
    acc[j] = make_float4(bv, bv, bv, bv);
  }
  const float* ip = in + (((size_t)b << 6) << 14) + px;
  const float* wp = wls + ((og << 2) << 6);
#pragma unroll 4
  for (int cc = 0; cc < 64; ++cc) {
    float4 xv = *(const float4*)(ip + ((size_t)cc << 14));
#pragma unroll
    for (int j = 0; j < 4; ++j) {
      float wv = wp[(j << 6) + cc];
      acc[j].x = fmaf(wv, xv.x, acc[j].x);
      acc[j].y = fmaf(wv, xv.y, acc[j].y);
      acc[j].z = fmaf(wv, xv.z, acc[j].z);
      acc[j].w = fmaf(wv, xv.w, acc[j].w);
    }
  }
#pragma unroll
  for (int j = 0; j < 4; ++j)
    *(float4*)(out + (((size_t)(b << 6) + ob + j) << 14) + px) = acc[j];
}

__global__ __launch_bounds__(256) void pw_k(const float* __restrict__ in,
                                            const float* __restrict__ w,
                                            const float* __restrict__ bias,
                                            float* __restrict__ out) {
  __shared__ float wls[16 * 64];
  pw_body(blockIdx.x, threadIdx.x, in, w, bias, out, wls);
}

__global__ __launch_bounds__(256) void pw3_k(const float* __restrict__ in0,
                                             const float* __restrict__ in1,
                                             const float* __restrict__ in2,
                                             const float* __restrict__ w0,
                                             const float* __restrict__ w1,
                                             const float* __restrict__ w2,
                                             const float* __restrict__ bi0,
                                             const float* __restrict__ bi1,
                                             const float* __restrict__ bi2,
                                             float* __restrict__ o0,
                                             float* __restrict__ o1,
                                             float* __restrict__ o2) {
  __shared__ float wls[16 * 64];
  int which = blockIdx.x >> 10;
  int bid = blockIdx.x & 1023;
  const float* in = (which == 0) ? in0 : (which == 1) ? in1 : in2;
  const float* w  = (which == 0) ? w0  : (which == 1) ? w1  : w2;
  const float* bi = (which == 0) ? bi0 : (which == 1) ? bi1 : bi2;
  float* out      = (which == 0) ? o0  : (which == 1) ? o1  : o2;
  pw_body(bid, threadIdx.x, in, w, bi, out, wls);
}

// ---------------------------------------------------------------------------
// gconv1_k: grouped 3x3 (o reads concat ch 2o,2o+1) + b1 + BN + ReLU -> t1
// ---------------------------------------------------------------------------
__global__ __launch_bounds__(256) void gconv1_k(const float* __restrict__ a,
                                                const float* __restrict__ w1,
                                                const float* __restrict__ b1,
                                                const float* __restrict__ g1,
                                                const float* __restrict__ be1,
                                                float* __restrict__ t1) {
  int bid = blockIdx.x;
  int b = bid >> 10;
  int r = bid & 1023;
  int o = r >> 4;
  int rc = r & 15;
  int tid = threadIdx.x;
  int px4 = tid & 31;
  int ry = tid >> 5;
  int y = (rc << 3) + ry;
  int x0 = px4 << 2;
  float bv = b1[o];
  float4 acc = make_float4(bv, bv, bv, bv);
#pragma unroll
  for (int ic = 0; ic < 2; ++ic) {
    const float* ap = a + ((size_t)(b * 128 + 2 * o + ic) << 14);
    const float* wr0 = w1 + o * 18 + ic * 9;
#pragma unroll
    for (int dy = 0; dy < 3; ++dy) {
      int yy = y + dy - 1;
      if ((unsigned)yy >= 128u) continue;
      const float* row = ap + (yy << 7);
      float4 mid = *(const float4*)(row + x0);
      float lf = (px4 > 0) ? row[x0 - 1] : 0.f;
      float rt = (px4 < 31) ? row[x0 + 4] : 0.f;
      float wa = wr0[dy * 3 + 0], wb = wr0[dy * 3 + 1], wc = wr0[dy * 3 + 2];
      acc.x += wa * lf    + wb * mid.x + wc * mid.y;
      acc.y += wa * mid.x + wb * mid.y + wc * mid.z;
      acc.z += wa * mid.y + wb * mid.z + wc * mid.w;
      acc.w += wa * mid.z + wb * mid.w + wc * rt;
    }
  }
  const float invs = 0.9999950000374997f;  // 1/sqrt(1+1e-5)
  float s = g1[o] * invs, be = be1[o];
  acc.x = fmaxf(acc.x * s + be, 0.f);
  acc.y = fmaxf(acc.y * s + be, 0.f);
  acc.z = fmaxf(acc.z * s + be, 0.f);
  acc.w = fmaxf(acc.w * s + be, 0.f);
  *(float4*)(t1 + (((size_t)(b << 6) + o) << 14) + (y << 7) + x0) = acc;
}

// ---------------------------------------------------------------------------
// dconv_k: depthwise 3x3 + b3 + BN + ReLU -> t2
// ---------------------------------------------------------------------------
__global__ __launch_bounds__(256) void dconv_k(const float* __restrict__ y2,
                                               const float* __restrict__ w3,
                                               const float* __restrict__ b3,
                                               const float* __restrict__ g2,
                                               const float* __restrict__ be2,
                                               float* __restrict__ t2) {
  int bid = blockIdx.x;
  int b = bid >> 10;
  int r = bid & 1023;
  int o = r >> 4;
  int rc = r & 15;
  int tid = threadIdx.x;
  int px4 = tid & 31;
  int ry = tid >> 5;
  int y = (rc << 3) + ry;
  int x0 = px4 << 2;
  float bv = b3[o];
  float4 acc = make_float4(bv, bv, bv, bv);
  const float* ap = y2 + (((size_t)(b << 6) + o) << 14);
  const float* wr0 = w3 + o * 9;
#pragma unroll
  for (int dy = 0; dy < 3; ++dy) {
    int yy = y + dy - 1;
    if ((unsigned)yy >= 128u) continue;
    const float* row = ap + (yy << 7);
    float4 mid = *(const float4*)(row + x0);
    float lf = (px4 > 0) ? row[x0 - 1] : 0.f;
    float rt = (px4 < 31) ? row[x0 + 4] : 0.f;
    float wa = wr0[dy * 3 + 0], wb = wr0[dy * 3 + 1], wc = wr0[dy * 3 + 2];
    acc.x += wa * lf    + wb * mid.x + wc * mid.y;
    acc.y += wa * mid.x + wb * mid.y + wc * mid.z;
    acc.z += wa * mid.y + wb * mid.z + wc * mid.w;
    acc.w += wa * mid.z + wb * mid.w + wc * rt;
  }
  const float invs = 0.9999950000374997f;
  float s = g2[o] * invs, be = be2[o];
  acc.x = fmaxf(acc.x * s + be, 0.f);
  acc.y = fmaxf(acc.y * s + be, 0.f);
  acc.z = fmaxf(acc.z * s + be, 0.f);
  acc.w = fmaxf(acc.w * s + be, 0.f);
  *(float4*)(t2 + (((size_t)(b << 6) + o) << 14) + (y << 7) + x0) = acc;
}

// ---------------------------------------------------------------------------
// PASS A via LDS dedup (r11 structure, 1/8-plane chunks for occupancy):
// block = (batch, channel c, eighth-plane hc). Stage xq/fgp/bgp over
// [h0-168, h0+2224) once (28.7KB LDS -> ~5 blocks/CU vs 2 at r11's 53.8KB),
// then compute every triple-group l whose window maps into this span.
// Block-edge quads recomputed bitwise-identically by neighbors; kk-crossing
// windows take the global-load slow path. Store layout/arith identical to r9.
// ---------------------------------------------------------------------------
__global__ __launch_bounds__(256) void passAlds_k(const float* __restrict__ xq,
                                                  const float* __restrict__ fgp,
                                                  const float* __restrict__ bgp,
                                                  _Float16* __restrict__ icols,
                                                  int b0) {
  __shared__ float LX[SPAN], LF[SPAN], LB[SPAN];
  int bid = blockIdx.x;
  int bl = bid >> 9;            // local batch within chunk
  int c  = (bid >> 3) & 63;
  int hc = bid & 7;
  int h0 = hc << 11;
  int b = b0 + bl;
  const float* xqb = xq + ((size_t)b << 20) + ((size_t)c << 14);
  const float* fgb = fgp + ((size_t)b << 20) + ((size_t)c << 14);
  const float* bgb = bgp + ((size_t)b << 20) + ((size_t)c << 14);
  _Float16* ic = icols + (size_t)bl * 9 * PLANE_H;
  int tid = threadIdx.x;

  // ---- stage (vector loads, per-element plane-bounds mask) ----
  for (int j4 = tid; j4 < (SPAN >> 2); j4 += 256) {
    int p0 = h0 - HALO + (j4 << 2);
    f4u xv = *(const f4u*)(xqb + p0);
    f4u fv = *(const f4u*)(fgb + p0);
    f4u bv = *(const f4u*)(bgb + p0);
#pragma unroll
    for (int e = 0; e < 4; ++e) {
      int ok = ((unsigned)(p0 + e) < 16384u);
      LX[(j4 << 2) + e] = ok ? xv[e] : 0.f;
      LF[(j4 << 2) + e] = ok ? fv[e] : 0.f;
      LB[(j4 << 2) + e] = ok ? bv[e] : 0.f;
    }
  }
  __syncthreads();

  // ---- quad worklist thresholds (uniform) ----
  int qs[9], pre[10];
  pre[0] = 0;
#pragma unroll
  for (int kk = 0; kk < 9; ++kk) {
    int ls = ((kk << 14) + h0 + 8) / 9;
    int le = ((kk << 14) + h0 + CHUNK + 8) / 9;
    qs[kk] = ls >> 2;
    pre[kk + 1] = pre[kk] + ((le + 3) >> 2) - qs[kk];
  }
  int Ctot = pre[9];

  for (int w = tid; w < Ctot; w += 256) {
    int kk = 0;
#pragma unroll
    for (int k2 = 1; k2 < 9; ++k2) kk += (w >= pre[k2]);
    int l4 = (qs[kk] + (w - pre[kk])) << 2;
    int ki = kk / 3, kj = kk - 3 * ki;
    int shift = ((ki - 1) << 7) + (kj - 1);
    h8 vout[9];
#pragma unroll
    for (int ql = 0; ql < 4; ++ql) {
      int l = l4 + ql;
      int t0l = 9 * l;
      float XV[9], SF[9], SB[9];
      if (((t0l >> 14) == kk) && (((t0l + 8) >> 14) == kk)) {
        // fast: window inside this kk region -> LDS
        int hwp0 = t0l - (kk << 14);
        int sbase = hwp0 + shift - h0 + HALO;
#pragma unroll
        for (int e = 0; e < 9; ++e) {
          int hwp = hwp0 + e;
          int sy = (hwp >> 7) + ki - 1;
          int sx = (hwp & 127) + kj - 1;
          int ok = ((unsigned)sy < 128u) & ((unsigned)sx < 128u);
          float xv = LX[sbase + e];
          float fv = LF[sbase + e];
          float bv = LB[sbase + e];
          XV[e] = ok ? xv : 0.f;
          SF[e] = ok ? xv * fv : 0.f;
          SB[e] = ok ? xv - bv : 0.f;
        }
      } else {
        // slow: kk-crossing (or chunk-edge rounding) -> global loads
#pragma unroll
        for (int e = 0; e < 9; ++e) {
          int t = t0l + e;
          int kke = t >> 14;
          int hwp = t & 16383;
          int kie = kke / 3, kje = kke - 3 * kie;
          int sy = (hwp >> 7) + kie - 1;
          int sx = (hwp & 127) + kje - 1;
          float xv = 0.f, sf = 0.f, sb = 0.f;
          if (((unsigned)sy < 128u) && ((unsigned)sx < 128u)) {
            int off = (sy << 7) + sx;
            xv = xqb[off];
            sf = xv * fgb[off];
            sb = xv - bgb[off];
          }
          XV[e] = xv; SF[e] = sf; SB[e] = sb;
        }
      }
#pragma unroll
      for (int tr = 0; tr < 3; ++tr) {
        int e = 3 * tr;
        float mf = fmaxf(fmaxf(SF[e], SF[e + 1]), SF[e + 2]);
        float e0 = __expf(SF[e] - mf), e1 = __expf(SF[e + 1] - mf), e2 = __expf(SF[e + 2] - mf);
        float rs = 0.125f / (e0 + e1 + e2);
        vout[e + 0][ql] = (_Float16)(e0 * rs * XV[e + 0]);
        vout[e + 1][ql] = (_Float16)(e1 * rs * XV[e + 1]);
        vout[e + 2][ql] = (_Float16)(e2 * rs * XV[e + 2]);
        float mb = fmaxf(fmaxf(SB[e], SB[e + 1]), SB[e + 2]);
        float g0 = __expf(SB[e] - mb), g1 = __expf(SB[e + 1] - mb), g2 = __expf(SB[e + 2] - mb);
        float rb = 0.125f / (g0 + g1 + g2);
        vout[e + 0][4 + ql] = (_Float16)(g0 * rb * XV[e + 0]);
        vout[e + 1][4 + ql] = (_Float16)(g1 * rb * XV[e + 1]);
        vout[e + 2][4 + ql] = (_Float16)(g2 * rb * XV[e + 2]);
      }
    }
    size_t goff = (size_t)((((c << 14) + l4) >> 2)) << 3;
#pragma unroll
    for (int m = 0; m < 9; ++m)
      __builtin_nontemporal_store(vout[m], (h8*)(ic + (size_t)m * PLANE_H + goff));
  }
}

// ---------------------------------------------------------------------------
// PASS B (8-wide, interleaved fp16 nt loads) — r9 verified version.
// tap u = 9*c2 + 3i + j -> plane mp = u>>6, n' = (u&63)*16384 + yp*128 + x.
// ---------------------------------------------------------------------------
__global__ __launch_bounds__(256) void passB_k(const _Float16* __restrict__ icols,
                                               float* __restrict__ a, int b0) {
  int bl = blockIdx.x >> 9;
  int idx = ((blockIdx.x & 511) << 8) + threadIdx.x;
  int b = b0 + bl;
  int c2 = idx >> 11;
  int hw0 = (idx << 3) & 16383;
  int y = hw0 >> 7, x0 = hw0 & 127;
  const _Float16* ic = icols + (size_t)bl * 9 * PLANE_H;
  float af[8], ab[8];
#pragma unroll
  for (int k = 0; k < 8; ++k) { af[k] = 0.f; ab[k] = 0.f; }
  h8 zero = {};
  int u9 = 9 * c2;
#pragma unroll
  for (int i = 0; i < 3; ++i) {
    int yp = y + 1 - i;
    if ((unsigned)yp >= 128u) continue;
#pragma unroll
    for (int j = 0; j < 3; ++j) {
      int u = u9 + 3 * i + j;
      int mp = u >> 6, rem = u & 63;
      int np = ((rem) << 14) + (yp << 7) + x0;
      const _Float16* p = ic + (size_t)mp * PLANE_H + ((size_t)np << 1);
      h8 G1 = __builtin_nontemporal_load((const h8*)p);
      h8 G2 = __builtin_nontemporal_load((const h8*)(p + 8));
      h8 G0 = (x0 > 0)   ? __builtin_nontemporal_load((const h8*)(p - 8))  : zero;
      h8 G3 = (x0 < 120) ? __builtin_nontemporal_load((const h8*)(p + 16)) : zero;
      float WF[10] = {(float)G0[3], (float)G1[0], (float)G1[1], (float)G1[2], (float)G1[3],
                      (float)G2[0], (float)G2[1], (float)G2[2], (float)G2[3], (float)G3[0]};
      float WB[10] = {(float)G0[7], (float)G1[4], (float)G1[5], (float)G1[6], (float)G1[7],
                      (float)G2[4], (float)G2[5], (float)G2[6], (float)G2[7], (float)G3[4]};
#pragma unroll
      for (int k = 0; k < 8; ++k) {
        af[k] += WF[k + 2 - j];
        ab[k] += WB[k + 2 - j];
      }
    }
  }
  float* aF = a + (((size_t)b * 128 + c2) << 14) + hw0;
  float* aB = a + (((size_t)b * 128 + 64 + c2) << 14) + hw0;
  *(float4*)(aF)     = make_float4(af[0], af[1], af[2], af[3]);
  *(float4*)(aF + 4) = make_float4(af[4], af[5], af[6], af[7]);
  *(float4*)(aB)     = make_float4(ab[0], ab[1], ab[2], ab[3]);
  *(float4*)(aB + 4) = make_float4(ab[4], ab[5], ab[6], ab[7]);
}

// ---------------------------------------------------------------------------
// Fallback fused attn+fold (verified) — used only if ws too small.
// ---------------------------------------------------------------------------
__device__ __forceinline__ void triel(const float* __restrict__ xqb,
                                      const float* __restrict__ fgb,
                                      const float* __restrict__ bgb,
                                      int fe, float& xv, float& sf, float& sb) {
  int u = fe >> 14;
  int hwp = fe & 16383;
  int c = u / 9;
  int kk = u - c * 9;
  int ki = kk / 3;
  int kj = kk - ki * 3;
  int sy = (hwp >> 7) + ki - 1;
  int sx = (hwp & 127) + kj - 1;
  if (((unsigned)sy < 128u) && ((unsigned)sx < 128u)) {
    int off = (c << 14) + (sy << 7) + sx;
    float xv_ = xqb[off];
    xv = xv_;
    sf = xv_ * fgb[off];
    sb = xv_ - bgb[off];
  } else {
    xv = 0.f; sf = 0.f; sb = 0.f;
  }
}

__global__ __launch_bounds__(256) void attnfold_k(const float* __restrict__ xq,
                                                  const float* __restrict__ fgp,
                                                  const float* __restrict__ bgp,
                                                  float* __restrict__ a) {
  int gidx = blockIdx.x * 256 + threadIdx.x;
  int hw = gidx & 16383;
  int bc = gidx >> 14;
  int c2 = bc & 63;
  int b = bc >> 6;
  int y = hw >> 7, x = hw & 127;
  const float* xqb = xq + (b << 20);
  const float* fgb = fgp + (b << 20);
  const float* bgb = bgp + (b << 20);
  float accf = 0.f, accb = 0.f;
#pragma unroll
  for (int i = 0; i < 3; ++i) {
    int yp = y + 1 - i;
    if ((unsigned)yp >= 128u) continue;
#pragma unroll
    for (int j = 0; j < 3; ++j) {
      int xp = x + 1 - j;
      if ((unsigned)xp >= 128u) continue;
      int g = ((c2 * 9 + i * 3 + j) << 14) + (yp << 7) + xp;
      int m = g >> 20;
      int n = g & 1048575;
      int f = n * 9 + m;
      int q = f % 3;
      int f0 = f - q;
      float xv0, sf0, sb0, xv1, sf1, sb1, xv2, sf2, sb2;
      triel(xqb, fgb, bgb, f0,     xv0, sf0, sb0);
      triel(xqb, fgb, bgb, f0 + 1, xv1, sf1, sb1);
      triel(xqb, fgb, bgb, f0 + 2, xv2, sf2, sb2);
      float xsel = (q == 0) ? xv0 : ((q == 1) ? xv1 : xv2);
      float mf = fmaxf(fmaxf(sf0, sf1), sf2);
      float ef0 = __expf(sf0 - mf), ef1 = __expf(sf1 - mf), ef2 = __expf(sf2 - mf);
      float self_f = (q == 0) ? ef0 : ((q == 1) ? ef1 : ef2);
      accf += self_f / (ef0 + ef1 + ef2) * xsel;
      float mb = fmaxf(fmaxf(sb0, sb1), sb2);
      float eb0 = __expf(sb0 - mb), eb1 = __expf(sb1 - mb), eb2 = __expf(sb2 - mb);
      float self_b = (q == 0) ? eb0 : ((q == 1) ? eb1 : eb2);
      accb += self_b / (eb0 + eb1 + eb2) * xsel;
    }
  }
  a[((b * 128 + c2) << 14) + hw] = accf * 0.125f;
  a[((b * 128 + 64 + c2) << 14) + hw] = accb * 0.125f;
}

// ---------------------------------------------------------------------------
extern "C" void kernel_launch(void* const* d_in, const int* in_sizes, int n_in,
                              void* d_out, int out_size, void* d_ws, size_t ws_size,
                              hipStream_t stream) {
  (void)in_sizes; (void)n_in; (void)out_size;
  const float* x      = (const float*)d_in[0];
  const float* fg     = (const float*)d_in[1];
  const float* bg     = (const float*)d_in[2];
  const float* w_x    = (const float*)d_in[3];
  const float* bias_x = (const float*)d_in[4];
  const float* w_f    = (const float*)d_in[5];
  const float* bias_f = (const float*)d_in[6];
  const float* w_b    = (const float*)d_in[7];
  const float* bias_b = (const float*)d_in[8];
  const float* w1     = (const float*)d_in[9];
  const float* b1     = (const float*)d_in[10];
  const float* g1     = (const float*)d_in[11];
  const float* be1    = (const float*)d_in[12];
  const float* w2     = (const float*)d_in[13];
  const float* b2     = (const float*)d_in[14];
  const float* w3     = (const float*)d_in[15];
  const float* b3     = (const float*)d_in[16];
  const float* g2     = (const float*)d_in[17];
  const float* be2    = (const float*)d_in[18];
  const float* w4     = (const float*)d_in[19];
  const float* b4     = (const float*)d_in[20];
  float* out = (float*)d_out;
  float* ws  = (float*)d_ws;

  const size_t NCHWf = (size_t)NB * 64 * HWSZ;  // 4,194,304 floats
  // 256-float front pad: staging vector loads can underrun the first plane
  // by up to 168 floats (masked lanes) — keep reads in-bounds.
  float* base = ws + 256;
  float* xq  = base;
  float* fgp = base + NCHWf;
  float* bgp = base + 2 * NCHWf;
  float* a   = base + 3 * NCHWf;                // 2*NCHWf floats
  _Float16* icolsbase = (_Float16*)(base + 5 * NCHWf);
  // dead-buffer reuse for the tail chain:
  float* t1 = fgp;   // fgp dead after passA
  float* y2 = xq;    // xq dead after passA
  float* t2 = bgp;   // bgp dead after passA

  dim3 blk(256);
  pw3_k<<<3 * NB * 256, blk, 0, stream>>>(x, fg, bg, w_x, w_f, w_b,
                                          bias_x, bias_f, bias_b, xq, fgp, bgp);

  // icols workspace: per batch 9 * 2^21 halfs = 37.75 MB.
  const size_t usedB = (5 * NCHWf + 512) * 4;
  const size_t perBatchColsB = 9 * PLANE_H * 2;  // bytes
  size_t availB = (ws_size > usedB) ? (ws_size - usedB) : 0;
  int fit = (int)(availB / perBatchColsB);
  if (fit > NB) fit = NB;

  if (fit >= 1) {
    for (int b0 = 0; b0 < NB; b0 += fit) {
      int nb = (NB - b0 < fit) ? (NB - b0) : fit;
      passAlds_k<<<nb * 512, blk, 0, stream>>>(xq, fgp, bgp, icolsbase, b0);
      passB_k<<<nb * 512, blk, 0, stream>>>(icolsbase, a, b0);
    }
  } else {
    attnfold_k<<<NB * 64 * HWSZ / 256, blk, 0, stream>>>(xq, fgp, bgp, a);
  }

  gconv1_k<<<NB * 1024, blk, 0, stream>>>(a, w1, b1, g1, be1, t1);
  pw_k<<<NB * 256, blk, 0, stream>>>(t1, w2, b2, y2);
  dconv_k<<<NB * 1024, blk, 0, stream>>>(y2, w3, b3, g2, be2, t2);
  pw_k<<<NB * 256, blk, 0, stream>>>(t2, w4, b4, out);
}

// Round 13
// 195.241 us; speedup vs baseline: 1.0438x; 1.0438x over previous
//
#include <hip/hip_runtime.h>

// Problem constants: B=4, C_IN=C=64, H=W=128, K=3, SCALE=0.125, EPS=1e-5
#define NB 4
#define HWSZ 16384   // 128*128

// 16B vector with only 4B alignment guarantee (gfx9+ supports unaligned dwordx4)
typedef float f4u __attribute__((ext_vector_type(4), aligned(4)));
// fp16 vectors for the interleaved cols tensor (stored fp16, computed fp32)
typedef _Float16 h8 __attribute__((ext_vector_type(8)));

// icols layout (r9-verified): flat cols g = m*2^20 + n; plane m stride 2^21
// halfs; group (n>>2) holds 16B = F0..F3|B0..B3.
#define PLANE_H ((size_t)1 << 21)
#define HALO 168
#define CHUNK 4096
#define SPAN 4440               // staged elements: [h0-168, h0+4096+176)
#define SPANP (SPAN + (SPAN >> 5) + 4)  // +1-per-32 padding (bank decorrelation)

// padded LDS index: stride 36 -> 37 floats between lanes (odd => 32 banks)
__device__ __forceinline__ int lp(int i) { return i + (i >> 5); }

// ---------------------------------------------------------------------------
// pw body: 1x1 conv (64 -> 64) + bias. 1024 blocks per op.
// ---------------------------------------------------------------------------
__device__ __forceinline__ void pw_body(int bid, int tid,
                                        const float* __restrict__ in,
                                        const float* __restrict__ w,
                                        const float* __restrict__ bias,
                                        float* __restrict__ out,
                                        float* wls) {
  int b = bid >> 8;
  int r = bid & 255;
  int oc = r >> 6;
  int pc = r & 63;
  int px4 = tid & 63;
  int og = tid >> 6;
  int px = (pc << 8) + (px4 << 2);
#pragma unroll
  for (int it = 0; it < 4; ++it)
    wls[(it << 8) + tid] = w[(oc << 10) + (it << 8) + tid];
  __syncthreads();
  int ob = (oc << 4) + (og << 2);
  float4 acc[4];
#pragma unroll
  for (int j = 0; j < 4; ++j) {
    float bv = bias[ob + j];
    acc[j] = make_float4(bv, bv, bv, bv);
  }
  const float* ip = in + (((size_t)b << 6) << 14) + px;
  const float* wp = wls + ((og << 2) << 6);
#pragma unroll 4
  for (int cc = 0; cc < 64; ++cc) {
    float4 xv = *(const float4*)(ip + ((size_t)cc << 14));
#pragma unroll
    for (int j = 0; j < 4; ++j) {
      float wv = wp[(j << 6) + cc];
      acc[j].x = fmaf(wv, xv.x, acc[j].x);
      acc[j].y = fmaf(wv, xv.y, acc[j].y);
      acc[j].z = fmaf(wv, xv.z, acc[j].z);
      acc[j].w = fmaf(wv, xv.w, acc[j].w);
    }
  }
#pragma unroll
  for (int j = 0; j < 4; ++j)
    *(float4*)(out + (((size_t)(b << 6) + ob + j) << 14) + px) = acc[j];
}

__global__ __launch_bounds__(256) void pw_k(const float* __restrict__ in,
                                            const float* __restrict__ w,
                                            const float* __restrict__ bias,
                                            float* __restrict__ out) {
  __shared__ float wls[16 * 64];
  pw_body(blockIdx.x, threadIdx.x, in, w, bias, out, wls);
}

__global__ __launch_bounds__(256) void pw3_k(const float* __restrict__ in0,
                                             const float* __restrict__ in1,
                                             const float* __restrict__ in2,
                                             const float* __restrict__ w0,
                                             const float* __restrict__ w1,
                                             const float* __restrict__ w2,
                                             const float* __restrict__ bi0,
                                             const float* __restrict__ bi1,
                                             const float* __restrict__ bi2,
                                             float* __restrict__ o0,
                                             float* __restrict__ o1,
                                             float* __restrict__ o2) {
  __shared__ float wls[16 * 64];
  int which = blockIdx.x >> 10;
  int bid = blockIdx.x & 1023;
  const float* in = (which == 0) ? in0 : (which == 1) ? in1 : in2;
  const float* w  = (which == 0) ? w0  : (which == 1) ? w1  : w2;
  const float* bi = (which == 0) ? bi0 : (which == 1) ? bi1 : bi2;
  float* out      = (which == 0) ? o0  : (which == 1) ? o1  : o2;
  pw_body(bid, threadIdx.x, in, w, bi, out, wls);
}

// ---------------------------------------------------------------------------
// gconv1_k: grouped 3x3 (o reads concat ch 2o,2o+1) + b1 + BN + ReLU -> t1
// ---------------------------------------------------------------------------
__global__ __launch_bounds__(256) void gconv1_k(const float* __restrict__ a,
                                                const float* __restrict__ w1,
                                                const float* __restrict__ b1,
                                                const float* __restrict__ g1,
                                                const float* __restrict__ be1,
                                                float* __restrict__ t1) {
  int bid = blockIdx.x;
  int b = bid >> 10;
  int r = bid & 1023;
  int o = r >> 4;
  int rc = r & 15;
  int tid = threadIdx.x;
  int px4 = tid & 31;
  int ry = tid >> 5;
  int y = (rc << 3) + ry;
  int x0 = px4 << 2;
  float bv = b1[o];
  float4 acc = make_float4(bv, bv, bv, bv);
#pragma unroll
  for (int ic = 0; ic < 2; ++ic) {
    const float* ap = a + ((size_t)(b * 128 + 2 * o + ic) << 14);
    const float* wr0 = w1 + o * 18 + ic * 9;
#pragma unroll
    for (int dy = 0; dy < 3; ++dy) {
      int yy = y + dy - 1;
      if ((unsigned)yy >= 128u) continue;
      const float* row = ap + (yy << 7);
      float4 mid = *(const float4*)(row + x0);
      float lf = (px4 > 0) ? row[x0 - 1] : 0.f;
      float rt = (px4 < 31) ? row[x0 + 4] : 0.f;
      float wa = wr0[dy * 3 + 0], wb = wr0[dy * 3 + 1], wc = wr0[dy * 3 + 2];
      acc.x += wa * lf    + wb * mid.x + wc * mid.y;
      acc.y += wa * mid.x + wb * mid.y + wc * mid.z;
      acc.z += wa * mid.y + wb * mid.z + wc * mid.w;
      acc.w += wa * mid.z + wb * mid.w + wc * rt;
    }
  }
  const float invs = 0.9999950000374997f;  // 1/sqrt(1+1e-5)
  float s = g1[o] * invs, be = be1[o];
  acc.x = fmaxf(acc.x * s + be, 0.f);
  acc.y = fmaxf(acc.y * s + be, 0.f);
  acc.z = fmaxf(acc.z * s + be, 0.f);
  acc.w = fmaxf(acc.w * s + be, 0.f);
  *(float4*)(t1 + (((size_t)(b << 6) + o) << 14) + (y << 7) + x0) = acc;
}

// ---------------------------------------------------------------------------
// dconv_k: depthwise 3x3 + b3 + BN + ReLU -> t2
// ---------------------------------------------------------------------------
__global__ __launch_bounds__(256) void dconv_k(const float* __restrict__ y2,
                                               const float* __restrict__ w3,
                                               const float* __restrict__ b3,
                                               const float* __restrict__ g2,
                                               const float* __restrict__ be2,
                                               float* __restrict__ t2) {
  int bid = blockIdx.x;
  int b = bid >> 10;
  int r = bid & 1023;
  int o = r >> 4;
  int rc = r & 15;
  int tid = threadIdx.x;
  int px4 = tid & 31;
  int ry = tid >> 5;
  int y = (rc << 3) + ry;
  int x0 = px4 << 2;
  float bv = b3[o];
  float4 acc = make_float4(bv, bv, bv, bv);
  const float* ap = y2 + (((size_t)(b << 6) + o) << 14);
  const float* wr0 = w3 + o * 9;
#pragma unroll
  for (int dy = 0; dy < 3; ++dy) {
    int yy = y + dy - 1;
    if ((unsigned)yy >= 128u) continue;
    const float* row = ap + (yy << 7);
    float4 mid = *(const float4*)(row + x0);
    float lf = (px4 > 0) ? row[x0 - 1] : 0.f;
    float rt = (px4 < 31) ? row[x0 + 4] : 0.f;
    float wa = wr0[dy * 3 + 0], wb = wr0[dy * 3 + 1], wc = wr0[dy * 3 + 2];
    acc.x += wa * lf    + wb * mid.x + wc * mid.y;
    acc.y += wa * mid.x + wb * mid.y + wc * mid.z;
    acc.z += wa * mid.y + wb * mid.z + wc * mid.w;
    acc.w += wa * mid.z + wb * mid.w + wc * rt;
  }
  const float invs = 0.9999950000374997f;
  float s = g2[o] * invs, be = be2[o];
  acc.x = fmaxf(acc.x * s + be, 0.f);
  acc.y = fmaxf(acc.y * s + be, 0.f);
  acc.z = fmaxf(acc.z * s + be, 0.f);
  acc.w = fmaxf(acc.w * s + be, 0.f);
  *(float4*)(t2 + (((size_t)(b << 6) + o) << 14) + (y << 7) + x0) = acc;
}

// ---------------------------------------------------------------------------
// PASS A via LDS dedup (r11 config: quarter-plane chunks), plus:
//  - padded LDS indices (i + (i>>5)): read stride 36 -> 37 floats between
//    lanes, odd => all 32 banks (was 8 banks / 8-way conflict, 9.6e6
//    conflict cycles measured at r12)
//  - v_rcp for the 6 softmax reciprocals per l (same formula in fast and
//    slow paths so block-edge duplicate quads stay bitwise identical)
// Worklists, store layout, arithmetic otherwise identical to r11 (verified).
// ---------------------------------------------------------------------------
__global__ __launch_bounds__(256) void passAlds_k(const float* __restrict__ xq,
                                                  const float* __restrict__ fgp,
                                                  const float* __restrict__ bgp,
                                                  _Float16* __restrict__ icols,
                                                  int b0) {
  __shared__ float LX[SPANP], LF[SPANP], LB[SPANP];
  int bid = blockIdx.x;
  int bl = bid >> 8;            // local batch within chunk
  int c  = (bid >> 2) & 63;
  int hc = bid & 3;
  int h0 = hc << 12;
  int b = b0 + bl;
  const float* xqb = xq + ((size_t)b << 20) + ((size_t)c << 14);
  const float* fgb = fgp + ((size_t)b << 20) + ((size_t)c << 14);
  const float* bgb = bgp + ((size_t)b << 20) + ((size_t)c << 14);
  _Float16* ic = icols + (size_t)bl * 9 * PLANE_H;
  int tid = threadIdx.x;

  // ---- stage (vector loads, per-element plane-bounds mask, padded store) ----
  for (int j4 = tid; j4 < (SPAN >> 2); j4 += 256) {
    int p0 = h0 - HALO + (j4 << 2);
    f4u xv = *(const f4u*)(xqb + p0);
    f4u fv = *(const f4u*)(fgb + p0);
    f4u bv = *(const f4u*)(bgb + p0);
#pragma unroll
    for (int e = 0; e < 4; ++e) {
      int ok = ((unsigned)(p0 + e) < 16384u);
      int pi = lp((j4 << 2) + e);
      LX[pi] = ok ? xv[e] : 0.f;
      LF[pi] = ok ? fv[e] : 0.f;
      LB[pi] = ok ? bv[e] : 0.f;
    }
  }
  __syncthreads();

  // ---- quad worklist thresholds (uniform) ----
  int qs[9], pre[10];
  pre[0] = 0;
#pragma unroll
  for (int kk = 0; kk < 9; ++kk) {
    int ls = ((kk << 14) + h0 + 8) / 9;
    int le = ((kk << 14) + h0 + CHUNK + 8) / 9;
    qs[kk] = ls >> 2;
    pre[kk + 1] = pre[kk] + ((le + 3) >> 2) - qs[kk];
  }
  int Ctot = pre[9];

  for (int w = tid; w < Ctot; w += 256) {
    int kk = 0;
#pragma unroll
    for (int k2 = 1; k2 < 9; ++k2) kk += (w >= pre[k2]);
    int l4 = (qs[kk] + (w - pre[kk])) << 2;
    int ki = kk / 3, kj = kk - 3 * ki;
    int shift = ((ki - 1) << 7) + (kj - 1);
    h8 vout[9];
#pragma unroll
    for (int ql = 0; ql < 4; ++ql) {
      int l = l4 + ql;
      int t0l = 9 * l;
      float XV[9], SF[9], SB[9];
      if (((t0l >> 14) == kk) && (((t0l + 8) >> 14) == kk)) {
        // fast: window inside this kk region -> LDS (padded index)
        int hwp0 = t0l - (kk << 14);
        int sbase = hwp0 + shift - h0 + HALO;
#pragma unroll
        for (int e = 0; e < 9; ++e) {
          int hwp = hwp0 + e;
          int sy = (hwp >> 7) + ki - 1;
          int sx = (hwp & 127) + kj - 1;
          int ok = ((unsigned)sy < 128u) & ((unsigned)sx < 128u);
          int pi = lp(sbase + e);
          float xv = LX[pi];
          float fv = LF[pi];
          float bv = LB[pi];
          XV[e] = ok ? xv : 0.f;
          SF[e] = ok ? xv * fv : 0.f;
          SB[e] = ok ? xv - bv : 0.f;
        }
      } else {
        // slow: kk-crossing (or chunk-edge rounding) -> global loads
#pragma unroll
        for (int e = 0; e < 9; ++e) {
          int t = t0l + e;
          int kke = t >> 14;
          int hwp = t & 16383;
          int kie = kke / 3, kje = kke - 3 * kie;
          int sy = (hwp >> 7) + kie - 1;
          int sx = (hwp & 127) + kje - 1;
          float xv = 0.f, sf = 0.f, sb = 0.f;
          if (((unsigned)sy < 128u) && ((unsigned)sx < 128u)) {
            int off = (sy << 7) + sx;
            xv = xqb[off];
            sf = xv * fgb[off];
            sb = xv - bgb[off];
          }
          XV[e] = xv; SF[e] = sf; SB[e] = sb;
        }
      }
#pragma unroll
      for (int tr = 0; tr < 3; ++tr) {
        int e = 3 * tr;
        float mf = fmaxf(fmaxf(SF[e], SF[e + 1]), SF[e + 2]);
        float e0 = __expf(SF[e] - mf), e1 = __expf(SF[e + 1] - mf), e2 = __expf(SF[e + 2] - mf);
        float rs = __builtin_amdgcn_rcpf(e0 + e1 + e2) * 0.125f;
        vout[e + 0][ql] = (_Float16)(e0 * rs * XV[e + 0]);
        vout[e + 1][ql] = (_Float16)(e1 * rs * XV[e + 1]);
        vout[e + 2][ql] = (_Float16)(e2 * rs * XV[e + 2]);
        float mb = fmaxf(fmaxf(SB[e], SB[e + 1]), SB[e + 2]);
        float g0 = __expf(SB[e] - mb), g1 = __expf(SB[e + 1] - mb), g2 = __expf(SB[e + 2] - mb);
        float rb = __builtin_amdgcn_rcpf(g0 + g1 + g2) * 0.125f;
        vout[e + 0][4 + ql] = (_Float16)(g0 * rb * XV[e + 0]);
        vout[e + 1][4 + ql] = (_Float16)(g1 * rb * XV[e + 1]);
        vout[e + 2][4 + ql] = (_Float16)(g2 * rb * XV[e + 2]);
      }
    }
    size_t goff = (size_t)((((c << 14) + l4) >> 2)) << 3;
#pragma unroll
    for (int m = 0; m < 9; ++m)
      __builtin_nontemporal_store(vout[m], (h8*)(ic + (size_t)m * PLANE_H + goff));
  }
}

// ---------------------------------------------------------------------------
// PASS B (8-wide, interleaved fp16 nt loads) — r9 verified version.
// tap u = 9*c2 + 3i + j -> plane mp = u>>6, n' = (u&63)*16384 + yp*128 + x.
// ---------------------------------------------------------------------------
__global__ __launch_bounds__(256) void passB_k(const _Float16* __restrict__ icols,
                                               float* __restrict__ a, int b0) {
  int bl = blockIdx.x >> 9;
  int idx = ((blockIdx.x & 511) << 8) + threadIdx.x;
  int b = b0 + bl;
  int c2 = idx >> 11;
  int hw0 = (idx << 3) & 16383;
  int y = hw0 >> 7, x0 = hw0 & 127;
  const _Float16* ic = icols + (size_t)bl * 9 * PLANE_H;
  float af[8], ab[8];
#pragma unroll
  for (int k = 0; k < 8; ++k) { af[k] = 0.f; ab[k] = 0.f; }
  h8 zero = {};
  int u9 = 9 * c2;
#pragma unroll
  for (int i = 0; i < 3; ++i) {
    int yp = y + 1 - i;
    if ((unsigned)yp >= 128u) continue;
#pragma unroll
    for (int j = 0; j < 3; ++j) {
      int u = u9 + 3 * i + j;
      int mp = u >> 6, rem = u & 63;
      int np = ((rem) << 14) + (yp << 7) + x0;
      const _Float16* p = ic + (size_t)mp * PLANE_H + ((size_t)np << 1);
      h8 G1 = __builtin_nontemporal_load((const h8*)p);
      h8 G2 = __builtin_nontemporal_load((const h8*)(p + 8));
      h8 G0 = (x0 > 0)   ? __builtin_nontemporal_load((const h8*)(p - 8))  : zero;
      h8 G3 = (x0 < 120) ? __builtin_nontemporal_load((const h8*)(p + 16)) : zero;
      float WF[10] = {(float)G0[3], (float)G1[0], (float)G1[1], (float)G1[2], (float)G1[3],
                      (float)G2[0], (float)G2[1], (float)G2[2], (float)G2[3], (float)G3[0]};
      float WB[10] = {(float)G0[7], (float)G1[4], (float)G1[5], (float)G1[6], (float)G1[7],
                      (float)G2[4], (float)G2[5], (float)G2[6], (float)G2[7], (float)G3[4]};
#pragma unroll
      for (int k = 0; k < 8; ++k) {
        af[k] += WF[k + 2 - j];
        ab[k] += WB[k + 2 - j];
      }
    }
  }
  float* aF = a + (((size_t)b * 128 + c2) << 14) + hw0;
  float* aB = a + (((size_t)b * 128 + 64 + c2) << 14) + hw0;
  *(float4*)(aF)     = make_float4(af[0], af[1], af[2], af[3]);
  *(float4*)(aF + 4) = make_float4(af[4], af[5], af[6], af[7]);
  *(float4*)(aB)     = make_float4(ab[0], ab[1], ab[2], ab[3]);
  *(float4*)(aB + 4) = make_float4(ab[4], ab[5], ab[6], ab[7]);
}

// ---------------------------------------------------------------------------
// Fallback fused attn+fold (verified) — used only if ws too small.
// ---------------------------------------------------------------------------
__device__ __forceinline__ void triel(const float* __restrict__ xqb,
                                      const float* __restrict__ fgb,
                                      const float* __restrict__ bgb,
                                      int fe, float& xv, float& sf, float& sb) {
  int u = fe >> 14;
  int hwp = fe & 16383;
  int c = u / 9;
  int kk = u - c * 9;
  int ki = kk / 3;
  int kj = kk - ki * 3;
  int sy = (hwp >> 7) + ki - 1;
  int sx = (hwp & 127) + kj - 1;
  if (((unsigned)sy < 128u) && ((unsigned)sx < 128u)) {
    int off = (c << 14) + (sy << 7) + sx;
    float xv_ = xqb[off];
    xv = xv_;
    sf = xv_ * fgb[off];
    sb = xv_ - bgb[off];
  } else {
    xv = 0.f; sf = 0.f; sb = 0.f;
  }
}

__global__ __launch_bounds__(256) void attnfold_k(const float* __restrict__ xq,
                                                  const float* __restrict__ fgp,
                                                  const float* __restrict__ bgp,
                                                  float* __restrict__ a) {
  int gidx = blockIdx.x * 256 + threadIdx.x;
  int hw = gidx & 16383;
  int bc = gidx >> 14;
  int c2 = bc & 63;
  int b = bc >> 6;
  int y = hw >> 7, x = hw & 127;
  const float* xqb = xq + (b << 20);
  const float* fgb = fgp + (b << 20);
  const float* bgb = bgp + (b << 20);
  float accf = 0.f, accb = 0.f;
#pragma unroll
  for (int i = 0; i < 3; ++i) {
    int yp = y + 1 - i;
    if ((unsigned)yp >= 128u) continue;
#pragma unroll
    for (int j = 0; j < 3; ++j) {
      int xp = x + 1 - j;
      if ((unsigned)xp >= 128u) continue;
      int g = ((c2 * 9 + i * 3 + j) << 14) + (yp << 7) + xp;
      int m = g >> 20;
      int n = g & 1048575;
      int f = n * 9 + m;
      int q = f % 3;
      int f0 = f - q;
      float xv0, sf0, sb0, xv1, sf1, sb1, xv2, sf2, sb2;
      triel(xqb, fgb, bgb, f0,     xv0, sf0, sb0);
      triel(xqb, fgb, bgb, f0 + 1, xv1, sf1, sb1);
      triel(xqb, fgb, bgb, f0 + 2, xv2, sf2, sb2);
      float xsel = (q == 0) ? xv0 : ((q == 1) ? xv1 : xv2);
      float mf = fmaxf(fmaxf(sf0, sf1), sf2);
      float ef0 = __expf(sf0 - mf), ef1 = __expf(sf1 - mf), ef2 = __expf(sf2 - mf);
      float self_f = (q == 0) ? ef0 : ((q == 1) ? ef1 : ef2);
      accf += self_f / (ef0 + ef1 + ef2) * xsel;
      float mb = fmaxf(fmaxf(sb0, sb1), sb2);
      float eb0 = __expf(sb0 - mb), eb1 = __expf(sb1 - mb), eb2 = __expf(sb2 - mb);
      float self_b = (q == 0) ? eb0 : ((q == 1) ? eb1 : eb2);
      accb += self_b / (eb0 + eb1 + eb2) * xsel;
    }
  }
  a[((b * 128 + c2) << 14) + hw] = accf * 0.125f;
  a[((b * 128 + 64 + c2) << 14) + hw] = accb * 0.125f;
}

// ---------------------------------------------------------------------------
extern "C" void kernel_launch(void* const* d_in, const int* in_sizes, int n_in,
                              void* d_out, int out_size, void* d_ws, size_t ws_size,
                              hipStream_t stream) {
  (void)in_sizes; (void)n_in; (void)out_size;
  const float* x      = (const float*)d_in[0];
  const float* fg     = (const float*)d_in[1];
  const float* bg     = (const float*)d_in[2];
  const float* w_x    = (const float*)d_in[3];
  const float* bias_x = (const float*)d_in[4];
  const float* w_f    = (const float*)d_in[5];
  const float* bias_f = (const float*)d_in[6];
  const float* w_b    = (const float*)d_in[7];
  const float* bias_b = (const float*)d_in[8];
  const float* w1     = (const float*)d_in[9];
  const float* b1     = (const float*)d_in[10];
  const float* g1     = (const float*)d_in[11];
  const float* be1    = (const float*)d_in[12];
  const float* w2     = (const float*)d_in[13];
  const float* b2     = (const float*)d_in[14];
  const float* w3     = (const float*)d_in[15];
  const float* b3     = (const float*)d_in[16];
  const float* g2     = (const float*)d_in[17];
  const float* be2    = (const float*)d_in[18];
  const float* w4     = (const float*)d_in[19];
  const float* b4     = (const float*)d_in[20];
  float* out = (float*)d_out;
  float* ws  = (float*)d_ws;

  const size_t NCHWf = (size_t)NB * 64 * HWSZ;  // 4,194,304 floats
  // 256-float front pad: staging vector loads can underrun the first plane
  // by up to 168 floats (masked lanes) — keep reads in-bounds.
  float* base = ws + 256;
  float* xq  = base;
  float* fgp = base + NCHWf;
  float* bgp = base + 2 * NCHWf;
  float* a   = base + 3 * NCHWf;                // 2*NCHWf floats
  _Float16* icolsbase = (_Float16*)(base + 5 * NCHWf);
  // dead-buffer reuse for the tail chain:
  float* t1 = fgp;   // fgp dead after passA
  float* y2 = xq;    // xq dead after passA
  float* t2 = bgp;   // bgp dead after passA

  dim3 blk(256);
  pw3_k<<<3 * NB * 256, blk, 0, stream>>>(x, fg, bg, w_x, w_f, w_b,
                                          bias_x, bias_f, bias_b, xq, fgp, bgp);

  // icols workspace: per batch 9 * 2^21 halfs = 37.75 MB.
  const size_t usedB = (5 * NCHWf + 512) * 4;
  const size_t perBatchColsB = 9 * PLANE_H * 2;  // bytes
  size_t availB = (ws_size > usedB) ? (ws_size - usedB) : 0;
  int fit = (int)(availB / perBatchColsB);
  if (fit > NB) fit = NB;

  if (fit >= 1) {
    for (int b0 = 0; b0 < NB; b0 += fit) {
      int nb = (NB - b0 < fit) ? (NB - b0) : fit;
      passAlds_k<<<nb * 256, blk, 0, stream>>>(xq, fgp, bgp, icolsbase, b0);
      passB_k<<<nb * 512, blk, 0, stream>>>(icolsbase, a, b0);
    }
  } else {
    attnfold_k<<<NB * 64 * HWSZ / 256, blk, 0, stream>>>(xq, fgp, bgp, a);
  }

  gconv1_k<<<NB * 1024, blk, 0, stream>>>(a, w1, b1, g1, be1, t1);
  pw_k<<<NB * 256, blk, 0, stream>>>(t1, w2, b2, y2);
  dconv_k<<<NB * 1024, blk, 0, stream>>>(y2, w3, b3, g2, be2, t2);
  pw_k<<<NB * 256, blk, 0, stream>>>(t2, w4, b4, out);
}

// Round 14
// 189.389 us; speedup vs baseline: 1.0761x; 1.0309x over previous
//
#include <hip/hip_runtime.h>

// Problem constants: B=4, C_IN=C=64, H=W=128, K=3, SCALE=0.125, EPS=1e-5
#define NB 4
#define HWSZ 16384   // 128*128

// 16B vector with only 4B alignment guarantee (gfx9+ supports unaligned dwordx4)
typedef float f4u __attribute__((ext_vector_type(4), aligned(4)));
// fp16 vectors for the interleaved cols tensor (stored fp16, computed fp32)
typedef _Float16 h8 __attribute__((ext_vector_type(8)));

// icols layout (r9-verified): flat cols g = m*2^20 + n; plane m stride 2^21
// halfs; group (n>>2) holds 16B = F0..F3|B0..B3.
#define PLANE_H ((size_t)1 << 21)
#define HALO 168
#define CHUNK 4096
#define SPAN 4440               // staged elements: [h0-168, h0+4096+176)
#define SPANP (SPAN + (SPAN >> 5) + 4)  // +1-per-32 padding (bank decorrelation)
#define ATHREADS 512            // passAlds block size (occupancy: 15% was the r13 limiter)

// padded LDS index: stride 36 -> 37 floats between lanes (odd => 32 banks)
__device__ __forceinline__ int lp(int i) { return i + (i >> 5); }

// ---------------------------------------------------------------------------
// pw body: 1x1 conv (64 -> 64) + bias. 1024 blocks per op.
// ---------------------------------------------------------------------------
__device__ __forceinline__ void pw_body(int bid, int tid,
                                        const float* __restrict__ in,
                                        const float* __restrict__ w,
                                        const float* __restrict__ bias,
                                        float* __restrict__ out,
                                        float* wls) {
  int b = bid >> 8;
  int r = bid & 255;
  int oc = r >> 6;
  int pc = r & 63;
  int px4 = tid & 63;
  int og = tid >> 6;
  int px = (pc << 8) + (px4 << 2);
#pragma unroll
  for (int it = 0; it < 4; ++it)
    wls[(it << 8) + tid] = w[(oc << 10) + (it << 8) + tid];
  __syncthreads();
  int ob = (oc << 4) + (og << 2);
  float4 acc[4];
#pragma unroll
  for (int j = 0; j < 4; ++j) {
    float bv = bias[ob + j];
    acc[j] = make_float4(bv, bv, bv, bv);
  }
  const float* ip = in + (((size_t)b << 6) << 14) + px;
  const float* wp = wls + ((og << 2) << 6);
#pragma unroll 4
  for (int cc = 0; cc < 64; ++cc) {
    float4 xv = *(const float4*)(ip + ((size_t)cc << 14));
#pragma unroll
    for (int j = 0; j < 4; ++j) {
      float wv = wp[(j << 6) + cc];
      acc[j].x = fmaf(wv, xv.x, acc[j].x);
      acc[j].y = fmaf(wv, xv.y, acc[j].y);
      acc[j].z = fmaf(wv, xv.z, acc[j].z);
      acc[j].w = fmaf(wv, xv.w, acc[j].w);
    }
  }
#pragma unroll
  for (int j = 0; j < 4; ++j)
    *(float4*)(out + (((size_t)(b << 6) + ob + j) << 14) + px) = acc[j];
}

__global__ __launch_bounds__(256) void pw_k(const float* __restrict__ in,
                                            const float* __restrict__ w,
                                            const float* __restrict__ bias,
                                            float* __restrict__ out) {
  __shared__ float wls[16 * 64];
  pw_body(blockIdx.x, threadIdx.x, in, w, bias, out, wls);
}

__global__ __launch_bounds__(256) void pw3_k(const float* __restrict__ in0,
                                             const float* __restrict__ in1,
                                             const float* __restrict__ in2,
                                             const float* __restrict__ w0,
                                             const float* __restrict__ w1,
                                             const float* __restrict__ w2,
                                             const float* __restrict__ bi0,
                                             const float* __restrict__ bi1,
                                             const float* __restrict__ bi2,
                                             float* __restrict__ o0,
                                             float* __restrict__ o1,
                                             float* __restrict__ o2) {
  __shared__ float wls[16 * 64];
  int which = blockIdx.x >> 10;
  int bid = blockIdx.x & 1023;
  const float* in = (which == 0) ? in0 : (which == 1) ? in1 : in2;
  const float* w  = (which == 0) ? w0  : (which == 1) ? w1  : w2;
  const float* bi = (which == 0) ? bi0 : (which == 1) ? bi1 : bi2;
  float* out      = (which == 0) ? o0  : (which == 1) ? o1  : o2;
  pw_body(bid, threadIdx.x, in, w, bi, out, wls);
}

// ---------------------------------------------------------------------------
// gconv1_k: grouped 3x3 (o reads concat ch 2o,2o+1) + b1 + BN + ReLU -> t1
// ---------------------------------------------------------------------------
__global__ __launch_bounds__(256) void gconv1_k(const float* __restrict__ a,
                                                const float* __restrict__ w1,
                                                const float* __restrict__ b1,
                                                const float* __restrict__ g1,
                                                const float* __restrict__ be1,
                                                float* __restrict__ t1) {
  int bid = blockIdx.x;
  int b = bid >> 10;
  int r = bid & 1023;
  int o = r >> 4;
  int rc = r & 15;
  int tid = threadIdx.x;
  int px4 = tid & 31;
  int ry = tid >> 5;
  int y = (rc << 3) + ry;
  int x0 = px4 << 2;
  float bv = b1[o];
  float4 acc = make_float4(bv, bv, bv, bv);
#pragma unroll
  for (int ic = 0; ic < 2; ++ic) {
    const float* ap = a + ((size_t)(b * 128 + 2 * o + ic) << 14);
    const float* wr0 = w1 + o * 18 + ic * 9;
#pragma unroll
    for (int dy = 0; dy < 3; ++dy) {
      int yy = y + dy - 1;
      if ((unsigned)yy >= 128u) continue;
      const float* row = ap + (yy << 7);
      float4 mid = *(const float4*)(row + x0);
      float lf = (px4 > 0) ? row[x0 - 1] : 0.f;
      float rt = (px4 < 31) ? row[x0 + 4] : 0.f;
      float wa = wr0[dy * 3 + 0], wb = wr0[dy * 3 + 1], wc = wr0[dy * 3 + 2];
      acc.x += wa * lf    + wb * mid.x + wc * mid.y;
      acc.y += wa * mid.x + wb * mid.y + wc * mid.z;
      acc.z += wa * mid.y + wb * mid.z + wc * mid.w;
      acc.w += wa * mid.z + wb * mid.w + wc * rt;
    }
  }
  const float invs = 0.9999950000374997f;  // 1/sqrt(1+1e-5)
  float s = g1[o] * invs, be = be1[o];
  acc.x = fmaxf(acc.x * s + be, 0.f);
  acc.y = fmaxf(acc.y * s + be, 0.f);
  acc.z = fmaxf(acc.z * s + be, 0.f);
  acc.w = fmaxf(acc.w * s + be, 0.f);
  *(float4*)(t1 + (((size_t)(b << 6) + o) << 14) + (y << 7) + x0) = acc;
}

// ---------------------------------------------------------------------------
// dconv_k: depthwise 3x3 + b3 + BN + ReLU -> t2
// ---------------------------------------------------------------------------
__global__ __launch_bounds__(256) void dconv_k(const float* __restrict__ y2,
                                               const float* __restrict__ w3,
                                               const float* __restrict__ b3,
                                               const float* __restrict__ g2,
                                               const float* __restrict__ be2,
                                               float* __restrict__ t2) {
  int bid = blockIdx.x;
  int b = bid >> 10;
  int r = bid & 1023;
  int o = r >> 4;
  int rc = r & 15;
  int tid = threadIdx.x;
  int px4 = tid & 31;
  int ry = tid >> 5;
  int y = (rc << 3) + ry;
  int x0 = px4 << 2;
  float bv = b3[o];
  float4 acc = make_float4(bv, bv, bv, bv);
  const float* ap = y2 + (((size_t)(b << 6) + o) << 14);
  const float* wr0 = w3 + o * 9;
#pragma unroll
  for (int dy = 0; dy < 3; ++dy) {
    int yy = y + dy - 1;
    if ((unsigned)yy >= 128u) continue;
    const float* row = ap + (yy << 7);
    float4 mid = *(const float4*)(row + x0);
    float lf = (px4 > 0) ? row[x0 - 1] : 0.f;
    float rt = (px4 < 31) ? row[x0 + 4] : 0.f;
    float wa = wr0[dy * 3 + 0], wb = wr0[dy * 3 + 1], wc = wr0[dy * 3 + 2];
    acc.x += wa * lf    + wb * mid.x + wc * mid.y;
    acc.y += wa * mid.x + wb * mid.y + wc * mid.z;
    acc.z += wa * mid.y + wb * mid.z + wc * mid.w;
    acc.w += wa * mid.z + wb * mid.w + wc * rt;
  }
  const float invs = 0.9999950000374997f;
  float s = g2[o] * invs, be = be2[o];
  acc.x = fmaxf(acc.x * s + be, 0.f);
  acc.y = fmaxf(acc.y * s + be, 0.f);
  acc.z = fmaxf(acc.z * s + be, 0.f);
  acc.w = fmaxf(acc.w * s + be, 0.f);
  *(float4*)(t2 + (((size_t)(b << 6) + o) << 14) + (y << 7) + x0) = acc;
}

// ---------------------------------------------------------------------------
// PASS A via LDS dedup (r13 kernel, 512 threads): same per-block work and
// LDS (55KB, 2 blocks/CU) but 8 waves/block -> 16 waves/CU = 4 waves/SIMD
// cap (was 2). r13 PMC showed OccupancyPercent 15% (~1.2 waves/SIMD) with
// issue-arithmetic ~7x below measured time => latency-bound on occupancy.
// Index math / store layout / arithmetic byte-identical to r13 (verified).
// ---------------------------------------------------------------------------
__global__ __launch_bounds__(ATHREADS) void passAlds_k(const float* __restrict__ xq,
                                                       const float* __restrict__ fgp,
                                                       const float* __restrict__ bgp,
                                                       _Float16* __restrict__ icols,
                                                       int b0) {
  __shared__ float LX[SPANP], LF[SPANP], LB[SPANP];
  int bid = blockIdx.x;
  int bl = bid >> 8;            // local batch within chunk
  int c  = (bid >> 2) & 63;
  int hc = bid & 3;
  int h0 = hc << 12;
  int b = b0 + bl;
  const float* xqb = xq + ((size_t)b << 20) + ((size_t)c << 14);
  const float* fgb = fgp + ((size_t)b << 20) + ((size_t)c << 14);
  const float* bgb = bgp + ((size_t)b << 20) + ((size_t)c << 14);
  _Float16* ic = icols + (size_t)bl * 9 * PLANE_H;
  int tid = threadIdx.x;

  // ---- stage (vector loads, per-element plane-bounds mask, padded store) ----
  for (int j4 = tid; j4 < (SPAN >> 2); j4 += ATHREADS) {
    int p0 = h0 - HALO + (j4 << 2);
    f4u xv = *(const f4u*)(xqb + p0);
    f4u fv = *(const f4u*)(fgb + p0);
    f4u bv = *(const f4u*)(bgb + p0);
#pragma unroll
    for (int e = 0; e < 4; ++e) {
      int ok = ((unsigned)(p0 + e) < 16384u);
      int pi = lp((j4 << 2) + e);
      LX[pi] = ok ? xv[e] : 0.f;
      LF[pi] = ok ? fv[e] : 0.f;
      LB[pi] = ok ? bv[e] : 0.f;
    }
  }
  __syncthreads();

  // ---- quad worklist thresholds (uniform) ----
  int qs[9], pre[10];
  pre[0] = 0;
#pragma unroll
  for (int kk = 0; kk < 9; ++kk) {
    int ls = ((kk << 14) + h0 + 8) / 9;
    int le = ((kk << 14) + h0 + CHUNK + 8) / 9;
    qs[kk] = ls >> 2;
    pre[kk + 1] = pre[kk] + ((le + 3) >> 2) - qs[kk];
  }
  int Ctot = pre[9];

  for (int w = tid; w < Ctot; w += ATHREADS) {
    int kk = 0;
#pragma unroll
    for (int k2 = 1; k2 < 9; ++k2) kk += (w >= pre[k2]);
    int l4 = (qs[kk] + (w - pre[kk])) << 2;
    int ki = kk / 3, kj = kk - 3 * ki;
    int shift = ((ki - 1) << 7) + (kj - 1);
    h8 vout[9];
#pragma unroll
    for (int ql = 0; ql < 4; ++ql) {
      int l = l4 + ql;
      int t0l = 9 * l;
      float XV[9], SF[9], SB[9];
      if (((t0l >> 14) == kk) && (((t0l + 8) >> 14) == kk)) {
        // fast: window inside this kk region -> LDS (padded index)
        int hwp0 = t0l - (kk << 14);
        int sbase = hwp0 + shift - h0 + HALO;
#pragma unroll
        for (int e = 0; e < 9; ++e) {
          int hwp = hwp0 + e;
          int sy = (hwp >> 7) + ki - 1;
          int sx = (hwp & 127) + kj - 1;
          int ok = ((unsigned)sy < 128u) & ((unsigned)sx < 128u);
          int pi = lp(sbase + e);
          float xv = LX[pi];
          float fv = LF[pi];
          float bv = LB[pi];
          XV[e] = ok ? xv : 0.f;
          SF[e] = ok ? xv * fv : 0.f;
          SB[e] = ok ? xv - bv : 0.f;
        }
      } else {
        // slow: kk-crossing (or chunk-edge rounding) -> global loads
#pragma unroll
        for (int e = 0; e < 9; ++e) {
          int t = t0l + e;
          int kke = t >> 14;
          int hwp = t & 16383;
          int kie = kke / 3, kje = kke - 3 * kie;
          int sy = (hwp >> 7) + kie - 1;
          int sx = (hwp & 127) + kje - 1;
          float xv = 0.f, sf = 0.f, sb = 0.f;
          if (((unsigned)sy < 128u) && ((unsigned)sx < 128u)) {
            int off = (sy << 7) + sx;
            xv = xqb[off];
            sf = xv * fgb[off];
            sb = xv - bgb[off];
          }
          XV[e] = xv; SF[e] = sf; SB[e] = sb;
        }
      }
#pragma unroll
      for (int tr = 0; tr < 3; ++tr) {
        int e = 3 * tr;
        float mf = fmaxf(fmaxf(SF[e], SF[e + 1]), SF[e + 2]);
        float e0 = __expf(SF[e] - mf), e1 = __expf(SF[e + 1] - mf), e2 = __expf(SF[e + 2] - mf);
        float rs = __builtin_amdgcn_rcpf(e0 + e1 + e2) * 0.125f;
        vout[e + 0][ql] = (_Float16)(e0 * rs * XV[e + 0]);
        vout[e + 1][ql] = (_Float16)(e1 * rs * XV[e + 1]);
        vout[e + 2][ql] = (_Float16)(e2 * rs * XV[e + 2]);
        float mb = fmaxf(fmaxf(SB[e], SB[e + 1]), SB[e + 2]);
        float g0 = __expf(SB[e] - mb), g1 = __expf(SB[e + 1] - mb), g2 = __expf(SB[e + 2] - mb);
        float rb = __builtin_amdgcn_rcpf(g0 + g1 + g2) * 0.125f;
        vout[e + 0][4 + ql] = (_Float16)(g0 * rb * XV[e + 0]);
        vout[e + 1][4 + ql] = (_Float16)(g1 * rb * XV[e + 1]);
        vout[e + 2][4 + ql] = (_Float16)(g2 * rb * XV[e + 2]);
      }
    }
    size_t goff = (size_t)((((c << 14) + l4) >> 2)) << 3;
#pragma unroll
    for (int m = 0; m < 9; ++m)
      __builtin_nontemporal_store(vout[m], (h8*)(ic + (size_t)m * PLANE_H + goff));
  }
}

// ---------------------------------------------------------------------------
// PASS B (8-wide, interleaved fp16 nt loads) — r9 verified version.
// tap u = 9*c2 + 3i + j -> plane mp = u>>6, n' = (u&63)*16384 + yp*128 + x.
// ---------------------------------------------------------------------------
__global__ __launch_bounds__(256) void passB_k(const _Float16* __restrict__ icols,
                                               float* __restrict__ a, int b0) {
  int bl = blockIdx.x >> 9;
  int idx = ((blockIdx.x & 511) << 8) + threadIdx.x;
  int b = b0 + bl;
  int c2 = idx >> 11;
  int hw0 = (idx << 3) & 16383;
  int y = hw0 >> 7, x0 = hw0 & 127;
  const _Float16* ic = icols + (size_t)bl * 9 * PLANE_H;
  float af[8], ab[8];
#pragma unroll
  for (int k = 0; k < 8; ++k) { af[k] = 0.f; ab[k] = 0.f; }
  h8 zero = {};
  int u9 = 9 * c2;
#pragma unroll
  for (int i = 0; i < 3; ++i) {
    int yp = y + 1 - i;
    if ((unsigned)yp >= 128u) continue;
#pragma unroll
    for (int j = 0; j < 3; ++j) {
      int u = u9 + 3 * i + j;
      int mp = u >> 6, rem = u & 63;
      int np = ((rem) << 14) + (yp << 7) + x0;
      const _Float16* p = ic + (size_t)mp * PLANE_H + ((size_t)np << 1);
      h8 G1 = __builtin_nontemporal_load((const h8*)p);
      h8 G2 = __builtin_nontemporal_load((const h8*)(p + 8));
      h8 G0 = (x0 > 0)   ? __builtin_nontemporal_load((const h8*)(p - 8))  : zero;
      h8 G3 = (x0 < 120) ? __builtin_nontemporal_load((const h8*)(p + 16)) : zero;
      float WF[10] = {(float)G0[3], (float)G1[0], (float)G1[1], (float)G1[2], (float)G1[3],
                      (float)G2[0], (float)G2[1], (float)G2[2], (float)G2[3], (float)G3[0]};
      float WB[10] = {(float)G0[7], (float)G1[4], (float)G1[5], (float)G1[6], (float)G1[7],
                      (float)G2[4], (float)G2[5], (float)G2[6], (float)G2[7], (float)G3[4]};
#pragma unroll
      for (int k = 0; k < 8; ++k) {
        af[k] += WF[k + 2 - j];
        ab[k] += WB[k + 2 - j];
      }
    }
  }
  float* aF = a + (((size_t)b * 128 + c2) << 14) + hw0;
  float* aB = a + (((size_t)b * 128 + 64 + c2) << 14) + hw0;
  *(float4*)(aF)     = make_float4(af[0], af[1], af[2], af[3]);
  *(float4*)(aF + 4) = make_float4(af[4], af[5], af[6], af[7]);
  *(float4*)(aB)     = make_float4(ab[0], ab[1], ab[2], ab[3]);
  *(float4*)(aB + 4) = make_float4(ab[4], ab[5], ab[6], ab[7]);
}

// ---------------------------------------------------------------------------
// Fallback fused attn+fold (verified) — used only if ws too small.
// ---------------------------------------------------------------------------
__device__ __forceinline__ void triel(const float* __restrict__ xqb,
                                      const float* __restrict__ fgb,
                                      const float* __restrict__ bgb,
                                      int fe, float& xv, float& sf, float& sb) {
  int u = fe >> 14;
  int hwp = fe & 16383;
  int c = u / 9;
  int kk = u - c * 9;
  int ki = kk / 3;
  int kj = kk - ki * 3;
  int sy = (hwp >> 7) + ki - 1;
  int sx = (hwp & 127) + kj - 1;
  if (((unsigned)sy < 128u) && ((unsigned)sx < 128u)) {
    int off = (c << 14) + (sy << 7) + sx;
    float xv_ = xqb[off];
    xv = xv_;
    sf = xv_ * fgb[off];
    sb = xv_ - bgb[off];
  } else {
    xv = 0.f; sf = 0.f; sb = 0.f;
  }
}

__global__ __launch_bounds__(256) void attnfold_k(const float* __restrict__ xq,
                                                  const float* __restrict__ fgp,
                                                  const float* __restrict__ bgp,
                                                  float* __restrict__ a) {
  int gidx = blockIdx.x * 256 + threadIdx.x;
  int hw = gidx & 16383;
  int bc = gidx >> 14;
  int c2 = bc & 63;
  int b = bc >> 6;
  int y = hw >> 7, x = hw & 127;
  const float* xqb = xq + (b << 20);
  const float* fgb = fgp + (b << 20);
  const float* bgb = bgp + (b << 20);
  float accf = 0.f, accb = 0.f;
#pragma unroll
  for (int i = 0; i < 3; ++i) {
    int yp = y + 1 - i;
    if ((unsigned)yp >= 128u) continue;
#pragma unroll
    for (int j = 0; j < 3; ++j) {
      int xp = x + 1 - j;
      if ((unsigned)xp >= 128u) continue;
      int g = ((c2 * 9 + i * 3 + j) << 14) + (yp << 7) + xp;
      int m = g >> 20;
      int n = g & 1048575;
      int f = n * 9 + m;
      int q = f % 3;
      int f0 = f - q;
      float xv0, sf0, sb0, xv1, sf1, sb1, xv2, sf2, sb2;
      triel(xqb, fgb, bgb, f0,     xv0, sf0, sb0);
      triel(xqb, fgb, bgb, f0 + 1, xv1, sf1, sb1);
      triel(xqb, fgb, bgb, f0 + 2, xv2, sf2, sb2);
      float xsel = (q == 0) ? xv0 : ((q == 1) ? xv1 : xv2);
      float mf = fmaxf(fmaxf(sf0, sf1), sf2);
      float ef0 = __expf(sf0 - mf), ef1 = __expf(sf1 - mf), ef2 = __expf(sf2 - mf);
      float self_f = (q == 0) ? ef0 : ((q == 1) ? ef1 : ef2);
      accf += self_f / (ef0 + ef1 + ef2) * xsel;
      float mb = fmaxf(fmaxf(sb0, sb1), sb2);
      float eb0 = __expf(sb0 - mb), eb1 = __expf(sb1 - mb), eb2 = __expf(sb2 - mb);
      float self_b = (q == 0) ? eb0 : ((q == 1) ? eb1 : eb2);
      accb += self_b / (eb0 + eb1 + eb2) * xsel;
    }
  }
  a[((b * 128 + c2) << 14) + hw] = accf * 0.125f;
  a[((b * 128 + 64 + c2) << 14) + hw] = accb * 0.125f;
}

// ---------------------------------------------------------------------------
extern "C" void kernel_launch(void* const* d_in, const int* in_sizes, int n_in,
                              void* d_out, int out_size, void* d_ws, size_t ws_size,
                              hipStream_t stream) {
  (void)in_sizes; (void)n_in; (void)out_size;
  const float* x      = (const float*)d_in[0];
  const float* fg     = (const float*)d_in[1];
  const float* bg     = (const float*)d_in[2];
  const float* w_x    = (const float*)d_in[3];
  const float* bias_x = (const float*)d_in[4];
  const float* w_f    = (const float*)d_in[5];
  const float* bias_f = (const float*)d_in[6];
  const float* w_b    = (const float*)d_in[7];
  const float* bias_b = (const float*)d_in[8];
  const float* w1     = (const float*)d_in[9];
  const float* b1     = (const float*)d_in[10];
  const float* g1     = (const float*)d_in[11];
  const float* be1    = (const float*)d_in[12];
  const float* w2     = (const float*)d_in[13];
  const float* b2     = (const float*)d_in[14];
  const float* w3     = (const float*)d_in[15];
  const float* b3     = (const float*)d_in[16];
  const float* g2     = (const float*)d_in[17];
  const float* be2    = (const float*)d_in[18];
  const float* w4     = (const float*)d_in[19];
  const float* b4     = (const float*)d_in[20];
  float* out = (float*)d_out;
  float* ws  = (float*)d_ws;

  const size_t NCHWf = (size_t)NB * 64 * HWSZ;  // 4,194,304 floats
  // 256-float front pad: staging vector loads can underrun the first plane
  // by up to 168 floats (masked lanes) — keep reads in-bounds.
  float* base = ws + 256;
  float* xq  = base;
  float* fgp = base + NCHWf;
  float* bgp = base + 2 * NCHWf;
  float* a   = base + 3 * NCHWf;                // 2*NCHWf floats
  _Float16* icolsbase = (_Float16*)(base + 5 * NCHWf);
  // dead-buffer reuse for the tail chain:
  float* t1 = fgp;   // fgp dead after passA
  float* y2 = xq;    // xq dead after passA
  float* t2 = bgp;   // bgp dead after passA

  dim3 blk(256);
  pw3_k<<<3 * NB * 256, blk, 0, stream>>>(x, fg, bg, w_x, w_f, w_b,
                                          bias_x, bias_f, bias_b, xq, fgp, bgp);

  // icols workspace: per batch 9 * 2^21 halfs = 37.75 MB.
  const size_t usedB = (5 * NCHWf + 512) * 4;
  const size_t perBatchColsB = 9 * PLANE_H * 2;  // bytes
  size_t availB = (ws_size > usedB) ? (ws_size - usedB) : 0;
  int fit = (int)(availB / perBatchColsB);
  if (fit > NB) fit = NB;

  if (fit >= 1) {
    for (int b0 = 0; b0 < NB; b0 += fit) {
      int nb = (NB - b0 < fit) ? (NB - b0) : fit;
      passAlds_k<<<nb * 256, dim3(ATHREADS), 0, stream>>>(xq, fgp, bgp, icolsbase, b0);
      passB_k<<<nb * 512, blk, 0, stream>>>(icolsbase, a, b0);
    }
  } else {
    attnfold_k<<<NB * 64 * HWSZ / 256, blk, 0, stream>>>(xq, fgp, bgp, a);
  }

  gconv1_k<<<NB * 1024, blk, 0, stream>>>(a, w1, b1, g1, be1, t1);
  pw_k<<<NB * 256, blk, 0, stream>>>(t1, w2, b2, y2);
  dconv_k<<<NB * 1024, blk, 0, stream>>>(y2, w3, b3, g2, be2, t2);
  pw_k<<<NB * 256, blk, 0, stream>>>(t2, w4, b4, out);
}